// Round 14
// baseline (45.306 us; speedup 1.0000x reference)
//
#include <hip/hip_runtime.h>
#include <math.h>

#define NN 512
#define DD 512
#define HH 1024
#define C2LOG2E 2.8853900817779268f   // 2*log2(e): exp(2y) = exp2(C*y)

typedef __attribute__((ext_vector_type(8))) short bf16x8;
typedef __attribute__((ext_vector_type(4))) float f32x4;

static __device__ __forceinline__ float rcp_fast(float x) {
    return __builtin_amdgcn_rcpf(x);   // v_rcp_f32
}
static __device__ __forceinline__ float exp2_fast(float x) {
    return __builtin_amdgcn_exp2f(x);  // v_exp_f32
}
static __device__ __forceinline__ ushort f2bf(float f) {   // RNE f32->bf16
    unsigned u = __float_as_uint(f);
    u += 0x7FFF + ((u >> 16) & 1);
    return (ushort)(u >> 16);
}
static __device__ __forceinline__ float bf2f(short u) {    // bf16->f32: 1 shl
    return __uint_as_float(((unsigned)(ushort)u) << 16);
}

// ---------------------------------------------------------------------------
// Kernel 0 (grid 384):
//   bx <  128: x -> xbs, bf16 PRE-SWIZZLED in MFMA A-fragment order
//   bx in [128,384): W1 -> Bts, bf16 fragment order over n-rows
// ---------------------------------------------------------------------------
__global__ __launch_bounds__(256) void k_convert(const float* __restrict__ x,
                                                 const float* __restrict__ W1,
                                                 short* __restrict__ xbs,
                                                 short* __restrict__ Bts) {
    __shared__ float ts[64][65];
    const int t = threadIdx.x;
    const int bx = blockIdx.x;
    if (bx < 128) {                        // xb swizzle: 32768 short8 chunks
        const int q = bx * 256 + t;
        const int g = q >> 10, ktc = (q >> 6) & 15, l = q & 63;
        const int i = g * 16 + (l & 15);
        const int k0 = ktc * 32 + (l >> 4) * 8;
        const float4 v0 = *(const float4*)&x[i * DD + k0];
        const float4 v1 = *(const float4*)&x[i * DD + k0 + 4];
        bf16x8 o;
        o[0] = (short)f2bf(v0.x); o[1] = (short)f2bf(v0.y);
        o[2] = (short)f2bf(v0.z); o[3] = (short)f2bf(v0.w);
        o[4] = (short)f2bf(v1.x); o[5] = (short)f2bf(v1.y);
        o[6] = (short)f2bf(v1.z); o[7] = (short)f2bf(v1.w);
        *(bf16x8*)&xbs[q * 8] = o;
        return;
    }
    const int tid = bx - 128;              // 8 k-tiles x 32 n-tiles
    const int k0 = (tid >> 5) * 64;
    const int nglob = (tid & 31) * 64;
    const int off = (nglob >= 1024) ? 512 : 0;
    const int nm = nglob & 1023;
#pragma unroll
    for (int u = 0; u < 4; ++u) {          // load 64(k) x 64(n) f32
        const int f4 = t + u * 256;
        const int r = f4 >> 4, c = (f4 & 15) * 4;
        *(float4*)&ts[r][c] = *(const float4*)&W1[(off + k0 + r) * HH + nm + c];
    }
    __syncthreads();
#pragma unroll
    for (int u = 0; u < 2; ++u) {          // 512 output chunks, frag order
        const int q = u * 256 + t;
        const int lg = q >> 7, lc = (q >> 6) & 1, l = q & 63;
        const int n_loc = lg * 16 + (l & 15);
        const int k_loc = lc * 32 + (l >> 4) * 8;
        bf16x8 o;
#pragma unroll
        for (int j = 0; j < 8; ++j) o[j] = (short)f2bf(ts[k_loc + j][n_loc]);
        const int gg = (nglob >> 4) + lg;
        const int ktc = (k0 >> 5) + lc;
        *(bf16x8*)&Bts[((gg * 16 + ktc) * 64 + l) * 8] = o;
    }
}

// ---------------------------------------------------------------------------
// Kernel 1: Ebf[i][n] bf16.
//   n <  1024: e~1 = exp2(C*h - 8) * rcp(W2[n])   (W2 folded into denominator)
//   n >= 1024: E2  = exp2(C*(h + b1[n-1024]))
// Fragment-order inputs -> every load is base + lane*16B + ktc*1KB (coalesced).
// Wave tile 16i x 32n, block = 4 waves in i. grid (8, 64) = 512 blocks.
// ---------------------------------------------------------------------------
__global__ __launch_bounds__(256) void k_gemm_mfma(const short* __restrict__ xbs,
                                                   const short* __restrict__ Bts,
                                                   const float* __restrict__ b1,
                                                   const float* __restrict__ W2,
                                                   short* __restrict__ Ebf) {
    const int t = threadIdx.x;
    const int w = t >> 6, l = t & 63;
    const int gi = blockIdx.x * 4 + w;     // i-group (16 rows)
    const int by = blockIdx.y;
    const int gn0 = by * 2;                // two n-groups of 16

    f32x4 acc[2] = {};
    const short* ap  = xbs + gi * 8192 + l * 8;
    const short* bp0 = Bts + (gn0 + 0) * 8192 + l * 8;
    const short* bp1 = Bts + (gn0 + 1) * 8192 + l * 8;
#pragma unroll
    for (int ktc = 0; ktc < 16; ++ktc) {
        const bf16x8 a = *(const bf16x8*)(ap + ktc * 512);
        acc[0] = __builtin_amdgcn_mfma_f32_16x16x32_bf16(a, *(const bf16x8*)(bp0 + ktc * 512), acc[0], 0, 0, 0);
        acc[1] = __builtin_amdgcn_mfma_f32_16x16x32_bf16(a, *(const bf16x8*)(bp1 + ktc * 512), acc[1], 0, 0, 0);
    }
    // C/D map: (reg r, lane l) -> row (l>>4)*4+r, col l&15 (m89-verified)
    const int lm = l & 15;
    const int orow = gi * 16 + (l >> 4) * 4;
    const bool second = (by >= 32);
#pragma unroll
    for (int c = 0; c < 2; ++c) {
        const int n = by * 32 + c * 16 + lm;
#pragma unroll
        for (int r = 0; r < 4; ++r) {
            float val;
            if (second) {
                val = exp2_fast(C2LOG2E * (acc[c][r] + b1[n - HH]));
            } else {
                val = exp2_fast(C2LOG2E * acc[c][r] - 8.0f) * rcp_fast(W2[n]);
            }
            Ebf[(orow + r) * (2 * HH) + n] = (short)f2bf(val);
        }
    }
}

// ---------------------------------------------------------------------------
// Kernel 2: partial scores -> PLAIN STORES to P[z] (no atomics; single-axis
// change vs R13 to isolate atomic-RMW cost). All-ones fraction tree:
// d_k = fma(e1_k, e2_k, q_k), q_k = 1/(256*W2[k]); one v_rcp per 8 h.
// P_z[i][j] = -2/256 * acc. grid (8,8,16) = 1024 blocks, LDS 18.7 KB.
// ---------------------------------------------------------------------------
__global__ __launch_bounds__(256) void k_score(const short* __restrict__ Ebf,
                                               const float* __restrict__ W2,
                                               float* __restrict__ P) {
    __shared__ short e1s[64][72];   // stride 36 dwords == 4 mod 32: 2-way max
    __shared__ short e2s[64][72];
    __shared__ float qs[64];
    const int t = threadIdx.x;
    const int i0 = blockIdx.x * 64, j0 = blockIdx.y * 64;
    const int hb = blockIdx.z * 64;
    const int tx = t & 15, ty = t >> 4;

#pragma unroll
    for (int u = 0; u < 2; ++u) {          // stage E1~ and E2, 64x64 bf16 each
        const int q = u * 256 + t;
        const int r = q >> 3, c8 = (q & 7) * 8;
        *(bf16x8*)&e1s[r][c8] = *(const bf16x8*)&Ebf[(i0 + r) * (2 * HH) + hb + c8];
        *(bf16x8*)&e2s[r][c8] = *(const bf16x8*)&Ebf[(j0 + r) * (2 * HH) + HH + hb + c8];
    }
    if (t < 64) qs[t] = rcp_fast(W2[hb + t]) * 0.00390625f;   // 1/(256*W2)
    __syncthreads();

    float acc[4][4] = {};
    const int ty4 = ty * 4;
#pragma unroll 2
    for (int s = 0; s < 8; ++s) {          // 8 h per step
        const int h8 = s * 8;
        float ef[4][8], ff[4][8];
#pragma unroll
        for (int m = 0; m < 4; ++m) {
            const bf16x8 v = *(const bf16x8*)&e1s[ty4 + m][h8];
#pragma unroll
            for (int j = 0; j < 8; ++j) ef[m][j] = bf2f(v[j]);
        }
#pragma unroll
        for (int n = 0; n < 4; ++n) {
            const bf16x8 v = *(const bf16x8*)&e2s[tx + n * 16][h8];
#pragma unroll
            for (int j = 0; j < 8; ++j) ff[n][j] = bf2f(v[j]);
        }
        float qv[8];
        *(float4*)&qv[0] = *(const float4*)&qs[h8];
        *(float4*)&qv[4] = *(const float4*)&qs[h8 + 4];
#pragma unroll
        for (int m = 0; m < 4; ++m) {
#pragma unroll
            for (int n = 0; n < 4; ++n) {
                const float* em = ef[m];
                const float* fn = ff[n];
                const float d0 = __builtin_fmaf(em[0], fn[0], qv[0]);
                const float d1 = __builtin_fmaf(em[1], fn[1], qv[1]);
                const float d2 = __builtin_fmaf(em[2], fn[2], qv[2]);
                const float d3 = __builtin_fmaf(em[3], fn[3], qv[3]);
                const float d4 = __builtin_fmaf(em[4], fn[4], qv[4]);
                const float d5 = __builtin_fmaf(em[5], fn[5], qv[5]);
                const float d6 = __builtin_fmaf(em[6], fn[6], qv[6]);
                const float d7 = __builtin_fmaf(em[7], fn[7], qv[7]);
                const float a01 = d0 + d1, a23 = d2 + d3;
                const float a45 = d4 + d5, a67 = d6 + d7;
                const float d01 = d0 * d1, d23 = d2 * d3;
                const float d45 = d4 * d5, d67 = d6 * d7;
                const float N1 = __builtin_fmaf(d23, a01, d01 * a23);
                const float N2 = __builtin_fmaf(d67, a45, d45 * a67);
                const float D1 = d01 * d23, D2 = d45 * d67;
                const float Nn = __builtin_fmaf(N1, D2, N2 * D1);
                const float Dd = D1 * D2;
                acc[m][n] = __builtin_fmaf(Nn, rcp_fast(Dd), acc[m][n]);
            }
        }
    }

    float* __restrict__ Pz = P + blockIdx.z * NN * NN;
#pragma unroll
    for (int m = 0; m < 4; ++m) {
        const int row = i0 + ty4 + m;
#pragma unroll
        for (int n = 0; n < 4; ++n) {
            const int col = j0 + tx + n * 16;
            Pz[row * NN + col] = -0.0078125f * acc[m][n];
        }
    }
}

// ---------------------------------------------------------------------------
// Kernel 3: out = (b2 + sum W2) + sum_z P_z. Per-block W2 reduction (cheap,
// L2-hot) supplies the constant; 16 float4 partial reads per thread.
// ---------------------------------------------------------------------------
__global__ __launch_bounds__(256) void k_combine(const float* __restrict__ P,
                                                 const float* __restrict__ W2,
                                                 const float* __restrict__ b2,
                                                 float* __restrict__ out) {
    __shared__ float red[256];
    const int t = threadIdx.x;
    red[t] = W2[t] + W2[t + 256] + W2[t + 512] + W2[t + 768];
    __syncthreads();
    for (int o = 128; o > 0; o >>= 1) {
        if (t < o) red[t] += red[t + o];
        __syncthreads();
    }
    const float base = b2[0] + red[0];
    const int idx = blockIdx.x * 256 + t;   // 65536 float4s
    float4 s; s.x = base; s.y = base; s.z = base; s.w = base;
#pragma unroll
    for (int z = 0; z < 16; ++z) {
        const float4 p = ((const float4*)(P + z * NN * NN))[idx];
        s.x += p.x; s.y += p.y; s.z += p.z; s.w += p.w;
    }
    ((float4*)out)[idx] = s;
}

extern "C" void kernel_launch(void* const* d_in, const int* in_sizes, int n_in,
                              void* d_out, int out_size, void* d_ws, size_t ws_size,
                              hipStream_t stream) {
    const float* x  = (const float*)d_in[0];
    const float* W1 = (const float*)d_in[1];
    const float* b1 = (const float*)d_in[2];
    const float* W2 = (const float*)d_in[3];
    const float* b2 = (const float*)d_in[4];
    float* out = (float*)d_out;

    short* Ebf = (short*)d_ws;                   // 512*2048 bf16 = 2 MB
    short* xbs = Ebf + NN * 2 * HH;              // 512*512 bf16  = 0.5 MB
    short* Bts = xbs + NN * DD;                  // 2048*512 bf16 = 2 MB
    float* P   = (float*)(Bts + 2 * HH * DD);    // 16 * 1 MB     = 16 MB

    k_convert<<<dim3(384), 256, 0, stream>>>(x, W1, xbs, Bts);
    k_gemm_mfma<<<dim3(8, 64), 256, 0, stream>>>(xbs, Bts, b1, W2, Ebf);
    k_score<<<dim3(8, 8, 16), 256, 0, stream>>>(Ebf, W2, P);
    k_combine<<<dim3(256), 256, 0, stream>>>(P, W2, b2, out);
}

// Round 15
// 41.560 us; speedup vs baseline: 1.0901x; 1.0901x over previous
//
#include <hip/hip_runtime.h>
#include <math.h>

#define NN 512
#define DD 512
#define HH 1024
#define C2LOG2E 2.8853900817779268f   // 2*log2(e): exp(2y) = exp2(C*y)

typedef __attribute__((ext_vector_type(8))) short bf16x8;
typedef __attribute__((ext_vector_type(4))) float f32x4;

static __device__ __forceinline__ float rcp_fast(float x) {
    return __builtin_amdgcn_rcpf(x);   // v_rcp_f32
}
static __device__ __forceinline__ float exp2_fast(float x) {
    return __builtin_amdgcn_exp2f(x);  // v_exp_f32
}
static __device__ __forceinline__ ushort f2bf(float f) {   // RNE f32->bf16
    unsigned u = __float_as_uint(f);
    u += 0x7FFF + ((u >> 16) & 1);
    return (ushort)(u >> 16);
}
static __device__ __forceinline__ float bf2f(short u) {    // bf16->f32: 1 shl
    return __uint_as_float(((unsigned)(ushort)u) << 16);
}

// ---------------------------------------------------------------------------
// Kernel 0 (grid 640):
//   bx <  128: x -> xbs, bf16 PRE-SWIZZLED in MFMA A-fragment order
//   bx in [128,384): W1 -> Bts, bf16 fragment order over n-rows
//   bx >= 384: out = b2 + sum(W2)  (constant term of the tanh identity)
// ---------------------------------------------------------------------------
__global__ __launch_bounds__(256) void k_convert(const float* __restrict__ x,
                                                 const float* __restrict__ W1,
                                                 const float* __restrict__ W2,
                                                 const float* __restrict__ b2,
                                                 short* __restrict__ xbs,
                                                 short* __restrict__ Bts,
                                                 float* __restrict__ out) {
    __shared__ float ts[64][65];
    const int t = threadIdx.x;
    const int bx = blockIdx.x;
    if (bx < 128) {                        // xb swizzle: 32768 short8 chunks
        const int q = bx * 256 + t;
        const int g = q >> 10, ktc = (q >> 6) & 15, l = q & 63;
        const int i = g * 16 + (l & 15);
        const int k0 = ktc * 32 + (l >> 4) * 8;
        const float4 v0 = *(const float4*)&x[i * DD + k0];
        const float4 v1 = *(const float4*)&x[i * DD + k0 + 4];
        bf16x8 o;
        o[0] = (short)f2bf(v0.x); o[1] = (short)f2bf(v0.y);
        o[2] = (short)f2bf(v0.z); o[3] = (short)f2bf(v0.w);
        o[4] = (short)f2bf(v1.x); o[5] = (short)f2bf(v1.y);
        o[6] = (short)f2bf(v1.z); o[7] = (short)f2bf(v1.w);
        *(bf16x8*)&xbs[q * 8] = o;
        return;
    }
    if (bx >= 384) {                       // out init: b2 + sum(W2)
        float* red = &ts[0][0];
        float s = W2[t] + W2[t + 256] + W2[t + 512] + W2[t + 768];
        red[t] = s;
        __syncthreads();
        for (int o = 128; o > 0; o >>= 1) {
            if (t < o) red[t] += red[t + o];
            __syncthreads();
        }
        const float v = b2[0] + red[0];
        const int f4 = (bx - 384) * 256 + t;
        float4 o4; o4.x = v; o4.y = v; o4.z = v; o4.w = v;
        ((float4*)out)[f4] = o4;
        return;
    }
    const int tid = bx - 128;              // 8 k-tiles x 32 n-tiles
    const int k0 = (tid >> 5) * 64;
    const int nglob = (tid & 31) * 64;
    const int off = (nglob >= 1024) ? 512 : 0;
    const int nm = nglob & 1023;
#pragma unroll
    for (int u = 0; u < 4; ++u) {          // load 64(k) x 64(n) f32
        const int f4 = t + u * 256;
        const int r = f4 >> 4, c = (f4 & 15) * 4;
        *(float4*)&ts[r][c] = *(const float4*)&W1[(off + k0 + r) * HH + nm + c];
    }
    __syncthreads();
#pragma unroll
    for (int u = 0; u < 2; ++u) {          // 512 output chunks, frag order
        const int q = u * 256 + t;
        const int lg = q >> 7, lc = (q >> 6) & 1, l = q & 63;
        const int n_loc = lg * 16 + (l & 15);
        const int k_loc = lc * 32 + (l >> 4) * 8;
        bf16x8 o;
#pragma unroll
        for (int j = 0; j < 8; ++j) o[j] = (short)f2bf(ts[k_loc + j][n_loc]);
        const int gg = (nglob >> 4) + lg;
        const int ktc = (k0 >> 5) + lc;
        *(bf16x8*)&Bts[((gg * 16 + ktc) * 64 + l) * 8] = o;
    }
}

// ---------------------------------------------------------------------------
// Kernel 1: Ebf[i][n] bf16.
//   n <  1024: e~1 = exp2(C*h - 8) * rcp(W2[n])   (W2 folded into denominator)
//   n >= 1024: E2  = exp2(C*(h + b1[n-1024]))
// Fragment-order inputs -> every load is base + lane*16B + ktc*1KB (coalesced).
// Wave tile 16i x 32n, block = 4 waves in i. grid (8, 64) = 512 blocks.
// ---------------------------------------------------------------------------
__global__ __launch_bounds__(256) void k_gemm_mfma(const short* __restrict__ xbs,
                                                   const short* __restrict__ Bts,
                                                   const float* __restrict__ b1,
                                                   const float* __restrict__ W2,
                                                   short* __restrict__ Ebf) {
    const int t = threadIdx.x;
    const int w = t >> 6, l = t & 63;
    const int gi = blockIdx.x * 4 + w;     // i-group (16 rows)
    const int by = blockIdx.y;
    const int gn0 = by * 2;                // two n-groups of 16

    f32x4 acc[2] = {};
    const short* ap  = xbs + gi * 8192 + l * 8;
    const short* bp0 = Bts + (gn0 + 0) * 8192 + l * 8;
    const short* bp1 = Bts + (gn0 + 1) * 8192 + l * 8;
#pragma unroll
    for (int ktc = 0; ktc < 16; ++ktc) {
        const bf16x8 a = *(const bf16x8*)(ap + ktc * 512);
        acc[0] = __builtin_amdgcn_mfma_f32_16x16x32_bf16(a, *(const bf16x8*)(bp0 + ktc * 512), acc[0], 0, 0, 0);
        acc[1] = __builtin_amdgcn_mfma_f32_16x16x32_bf16(a, *(const bf16x8*)(bp1 + ktc * 512), acc[1], 0, 0, 0);
    }
    // C/D map: (reg r, lane l) -> row (l>>4)*4+r, col l&15 (m89-verified)
    const int lm = l & 15;
    const int orow = gi * 16 + (l >> 4) * 4;
    const bool second = (by >= 32);
#pragma unroll
    for (int c = 0; c < 2; ++c) {
        const int n = by * 32 + c * 16 + lm;
#pragma unroll
        for (int r = 0; r < 4; ++r) {
            float val;
            if (second) {
                val = exp2_fast(C2LOG2E * (acc[c][r] + b1[n - HH]));
            } else {
                val = exp2_fast(C2LOG2E * acc[c][r] - 8.0f) * rcp_fast(W2[n]);
            }
            Ebf[(orow + r) * (2 * HH) + n] = (short)f2bf(val);
        }
    }
}

// ---------------------------------------------------------------------------
// Kernel 2: partial scores, atomically accumulated into out. (R13 revert)
// 4x4 micro on 64x64 tile; all-ones fraction tree: d_k = fma(e1_k,e2_k,q_k),
// q_k = 1/(256*W2[k]); one v_rcp per 8 h. out += -2/256 * acc.
// s_setprio(1) around the compute loop (blocks are barrier-independent after
// staging -> attn-like regime where setprio measured +4-7%, m191).
// grid (8,8,16) = 1024 blocks, LDS 18.7 KB.
// ---------------------------------------------------------------------------
__global__ __launch_bounds__(256) void k_score(const short* __restrict__ Ebf,
                                               const float* __restrict__ W2,
                                               float* __restrict__ out) {
    __shared__ short e1s[64][72];   // stride 36 dwords == 4 mod 32: 2-way max
    __shared__ short e2s[64][72];
    __shared__ float qs[64];
    const int t = threadIdx.x;
    const int i0 = blockIdx.x * 64, j0 = blockIdx.y * 64;
    const int hb = blockIdx.z * 64;
    const int tx = t & 15, ty = t >> 4;

#pragma unroll
    for (int u = 0; u < 2; ++u) {          // stage E1~ and E2, 64x64 bf16 each
        const int q = u * 256 + t;
        const int r = q >> 3, c8 = (q & 7) * 8;
        *(bf16x8*)&e1s[r][c8] = *(const bf16x8*)&Ebf[(i0 + r) * (2 * HH) + hb + c8];
        *(bf16x8*)&e2s[r][c8] = *(const bf16x8*)&Ebf[(j0 + r) * (2 * HH) + HH + hb + c8];
    }
    if (t < 64) qs[t] = rcp_fast(W2[hb + t]) * 0.00390625f;   // 1/(256*W2)
    __syncthreads();

    float acc[4][4] = {};
    const int ty4 = ty * 4;
    __builtin_amdgcn_s_setprio(1);
#pragma unroll 2
    for (int s = 0; s < 8; ++s) {          // 8 h per step
        const int h8 = s * 8;
        float ef[4][8], ff[4][8];
#pragma unroll
        for (int m = 0; m < 4; ++m) {
            const bf16x8 v = *(const bf16x8*)&e1s[ty4 + m][h8];
#pragma unroll
            for (int j = 0; j < 8; ++j) ef[m][j] = bf2f(v[j]);
        }
#pragma unroll
        for (int n = 0; n < 4; ++n) {
            const bf16x8 v = *(const bf16x8*)&e2s[tx + n * 16][h8];
#pragma unroll
            for (int j = 0; j < 8; ++j) ff[n][j] = bf2f(v[j]);
        }
        float qv[8];
        *(float4*)&qv[0] = *(const float4*)&qs[h8];
        *(float4*)&qv[4] = *(const float4*)&qs[h8 + 4];
#pragma unroll
        for (int m = 0; m < 4; ++m) {
#pragma unroll
            for (int n = 0; n < 4; ++n) {
                const float* em = ef[m];
                const float* fn = ff[n];
                const float d0 = __builtin_fmaf(em[0], fn[0], qv[0]);
                const float d1 = __builtin_fmaf(em[1], fn[1], qv[1]);
                const float d2 = __builtin_fmaf(em[2], fn[2], qv[2]);
                const float d3 = __builtin_fmaf(em[3], fn[3], qv[3]);
                const float d4 = __builtin_fmaf(em[4], fn[4], qv[4]);
                const float d5 = __builtin_fmaf(em[5], fn[5], qv[5]);
                const float d6 = __builtin_fmaf(em[6], fn[6], qv[6]);
                const float d7 = __builtin_fmaf(em[7], fn[7], qv[7]);
                const float a01 = d0 + d1, a23 = d2 + d3;
                const float a45 = d4 + d5, a67 = d6 + d7;
                const float d01 = d0 * d1, d23 = d2 * d3;
                const float d45 = d4 * d5, d67 = d6 * d7;
                const float N1 = __builtin_fmaf(d23, a01, d01 * a23);
                const float N2 = __builtin_fmaf(d67, a45, d45 * a67);
                const float D1 = d01 * d23, D2 = d45 * d67;
                const float Nn = __builtin_fmaf(N1, D2, N2 * D1);
                const float Dd = D1 * D2;
                acc[m][n] = __builtin_fmaf(Nn, rcp_fast(Dd), acc[m][n]);
            }
        }
    }
    __builtin_amdgcn_s_setprio(0);

#pragma unroll
    for (int m = 0; m < 4; ++m) {
        const int row = i0 + ty4 + m;
#pragma unroll
        for (int n = 0; n < 4; ++n) {
            const int col = j0 + tx + n * 16;
            atomicAdd(&out[row * NN + col], -0.0078125f * acc[m][n]);
        }
    }
}

extern "C" void kernel_launch(void* const* d_in, const int* in_sizes, int n_in,
                              void* d_out, int out_size, void* d_ws, size_t ws_size,
                              hipStream_t stream) {
    const float* x  = (const float*)d_in[0];
    const float* W1 = (const float*)d_in[1];
    const float* b1 = (const float*)d_in[2];
    const float* W2 = (const float*)d_in[3];
    const float* b2 = (const float*)d_in[4];
    float* out = (float*)d_out;

    short* Ebf = (short*)d_ws;                   // 512*2048 bf16 = 2 MB
    short* xbs = Ebf + NN * 2 * HH;              // 512*512 bf16  = 0.5 MB
    short* Bts = xbs + NN * DD;                  // 2048*512 bf16 = 2 MB

    k_convert<<<dim3(640), 256, 0, stream>>>(x, W1, W2, b2, xbs, Bts, out);
    k_gemm_mfma<<<dim3(8, 64), 256, 0, stream>>>(xbs, Bts, b1, W2, Ebf);
    k_score<<<dim3(8, 8, 16), 256, 0, stream>>>(Ebf, W2, out);
}